// Round 1
// 244.901 us; speedup vs baseline: 1.1186x; 1.1186x over previous
//
#include <hip/hip_runtime.h>
#include <stdint.h>

// ============================================================================
// ExpertMLP: out = relu(x @ W_fc^T)^2 @ W_proj^T    (fp32 in/out, bf16 MFMA)
// R7: 256-wide 8-phase pipelined GEMM (HK-style T2+T3+T4+T5 stack in plain HIP)
//   - BM=256, BK=64, 8 waves (2M x 4N), 512 threads
//   - kh-major LDS tiles [kh][rows][32k], XOR bank swizzle (T2), both-sides
//   - 4 phases/K-tile: {8,4,8,4} ds_read_b128 + 1 half-tile gload_lds each
//   - counted vmcnt(KEEP) once per K-tile, never 0 in steady state (T4)
//   - s_setprio(1) around each 16-MFMA cluster (T5), XCD block swizzle (T1)
//   GEMM1: NF=4 (BN=256, grid 16x32).  GEMM2: NF=2 (BN=128, grid 8x32 = 1/CU).
// ws: h[64Mi] | x_bf[16Mi] | wfc_bf[8Mi] | wproj_bf[8Mi] = 96 MiB.
// ============================================================================

typedef __attribute__((ext_vector_type(8))) short bf16x8;   // 8 bf16 = 4 VGPRs
typedef __attribute__((ext_vector_type(4))) float f32x4;    // MFMA C/D

typedef const __attribute__((address_space(1))) unsigned int* gas_u32p;
typedef __attribute__((address_space(3))) unsigned int* las_u32p;

__device__ __forceinline__ void load16_to_lds(const void* gptr, void* lptr) {
    // async global->LDS, 16 B per lane; LDS dst = wave-uniform base + lane*16
    __builtin_amdgcn_global_load_lds((gas_u32p)gptr, (las_u32p)lptr, 16, 0, 0);
}

__device__ __forceinline__ unsigned short f2bf(float f) {
    unsigned int u = __float_as_uint(f);
    u += 0x7FFFu + ((u >> 16) & 1u);   // RNE; finite inputs
    return (unsigned short)(u >> 16);
}

// --------------------------------------------------------------------------
// Single fused fp32->bf16 prepass: x (2M float4) | W_fc (1M) | W_proj (1M).
// --------------------------------------------------------------------------
__global__ void cvt_all(const float4* __restrict__ x,  ushort4* __restrict__ xb,
                        const float4* __restrict__ wf, ushort4* __restrict__ wfb,
                        const float4* __restrict__ wp, ushort4* __restrict__ wpb)
{
    const int base = blockIdx.x * 1024 + threadIdx.x;
    #pragma unroll
    for (int j = 0; j < 4; j++) {
        const int i = base + j * 256;
        const float4* s; ushort4* d; int k;
        if (i < (1 << 21))            { s = x;  d = xb;  k = i; }
        else if (i < 3 * (1 << 20))   { s = wf; d = wfb; k = i - (1 << 21); }
        else                          { s = wp; d = wpb; k = i - 3 * (1 << 20); }
        float4 v = s[k];
        ushort4 o;
        o.x = f2bf(v.x); o.y = f2bf(v.y); o.z = f2bf(v.z); o.w = f2bf(v.w);
        d[k] = o;
    }
}

#define LGKM0_FENCE() do { \
    asm volatile("s_waitcnt lgkmcnt(0)" ::: "memory"); \
    __builtin_amdgcn_sched_barrier(0); } while (0)

// --------------------------------------------------------------------------
// C[M,N] = A[M,K] . B[N,K]^T   bf16 in, fp32 accum; RELU2/OUT_BF16 epilogue.
// NF = per-wave N fragments (4 -> BN=256, 2 -> BN=128).  Requires K%128==0,
// M%256==0, N%BN==0, grid (N/BN, M/256), 512 threads.
// LDS per buffer: A [2kh][256][32k] (32 KiB) + B [2kh][BN][32k].
// Half-tile order per tile: h1=B.kh0, h2=A.kh0, h3=B.kh1, h4=A.kh1.
// Group t (4 phases, reads buf[t&1]):
//   p1 reads B.kh0(all)+A.mh0.kh0, stages (t+1).h4 -> buf[t&1^1]   (dead, safe)
//   p2 reads A.mh1.kh0,            stages (t+2).h1 -> buf[t&1]     (dead @p1)
//   p3 reads B.kh1(all)+A.mh0.kh1, stages (t+2).h2 -> buf[t&1]     (dead @p2)
//   p4 reads A.mh1.kh1,            stages (t+2).h3 -> buf[t&1]     (dead @p3)
//   end: vmcnt(KEEP) retires tile t+1 completely, keeps (t+2).h1-3 in flight.
// --------------------------------------------------------------------------
template<int NF, bool RELU2, bool OUT_BF16>
__global__ __launch_bounds__(512, 2)
void gemm8p(const unsigned short* __restrict__ A,
            const unsigned short* __restrict__ B,
            void* __restrict__ Cv, int M, int N, int K)
{
    constexpr int BM   = 256;
    constexpr int BN   = 64 * NF;
    constexpr int CB   = BN / 128;         // gload_lds calls per B half-tile
    constexpr int AKH  = 16384;            // A kh-region bytes (256r x 32k x 2B)
    constexpr int BKH  = BN * 64;          // B kh-region bytes
    constexpr int BOFF = 2 * AKH;
    constexpr int BUFB = 2 * AKH + 2 * BKH;
    constexpr int KEEP = 2 + 2 * CB;       // loads of 3 in-flight half-tiles
    (void)M;

    __shared__ char lds[2 * BUFB];

    const int tid  = threadIdx.x;
    const int lane = tid & 63;
    const int wave = tid >> 6;
    const int wm   = wave >> 2;            // 0..1 (M wave row)
    const int wn   = wave & 3;             // 0..3 (N wave col)
    const int quad = lane >> 4;
    const int m16  = lane & 15;

    // T1: XCD-aware block swizzle (both grids are %8==0)
    const int gx = gridDim.x;
    int flat = blockIdx.y * gx + blockIdx.x;
    const int cpx = (gx * gridDim.y) >> 3;
    flat = (flat & 7) * cpx + (flat >> 3);
    const long bm0 = (long)(flat / gx) * BM;
    const long bn0 = (long)(flat % gx) * BN;

    // staging geometry: thread -> (row = tid/4 [+128 on call 1], 16B chunk).
    // source pre-swizzled so linear gload_lds dst + swizzled ds_read agree.
    const int srow   = tid >> 2;                       // 0..127
    const int schunk = (tid & 3) ^ ((tid >> 3) & 3);   // = chunk ^ (row>>1)&3
    const unsigned short* gA = A + (bm0 + srow) * (long)K + schunk * 8;
    const unsigned short* gB = B + (bn0 + srow) * (long)K + schunk * 8;
    char* lbase = (char*)lds;

    // T2: swizzled ds_read_b128 offsets within a kh-region (row*64 + quad*16)
    int offA[8], offB[NF];
    #pragma unroll
    for (int i = 0; i < 8; i++) {
        const int lo = (wm * 128 + i * 16 + m16) * 64 + quad * 16;
        offA[i] = lo ^ (((lo >> 7) & 3) << 4);
    }
    #pragma unroll
    for (int j = 0; j < NF; j++) {
        const int lo = (wn * 16 * NF + j * 16 + m16) * 64 + quad * 16;
        offB[j] = lo ^ (((lo >> 7) & 3) << 4);
    }

    f32x4 acc[8][NF];
    #pragma unroll
    for (int i = 0; i < 8; i++)
        #pragma unroll
        for (int j = 0; j < NF; j++)
            acc[i][j] = (f32x4)0.0f;

    const int NT = K >> 6;

    #define STAGE_A(t, kh) do { \
        char* _d = lbase + ((t) & 1) * BUFB + (kh) * AKH + tid * 16; \
        const unsigned short* _s = gA + (long)(t) * 64 + (kh) * 32; \
        load16_to_lds(_s, _d); \
        load16_to_lds(_s + 128l * K, _d + 8192); } while (0)

    #define STAGE_B(t, kh) do { \
        char* _d = lbase + ((t) & 1) * BUFB + BOFF + (kh) * BKH + tid * 16; \
        const unsigned short* _s = gB + (long)(t) * 64 + (kh) * 32; \
        load16_to_lds(_s, _d); \
        if (CB == 2) load16_to_lds(_s + 128l * K, _d + 8192); } while (0)

    // prologue: tile0 h1..h4 + tile1 h1..h3; retire tile0, keep tile1 partials
    STAGE_B(0, 0); STAGE_A(0, 0); STAGE_B(0, 1); STAGE_A(0, 1);
    if (NT > 1) {
        STAGE_B(1, 0); STAGE_A(1, 0); STAGE_B(1, 1);
        asm volatile("s_waitcnt vmcnt(%0)" :: "i"(KEEP) : "memory");
    } else {
        asm volatile("s_waitcnt vmcnt(0)" ::: "memory");
    }
    __builtin_amdgcn_sched_barrier(0);
    __builtin_amdgcn_s_barrier();

    for (int t = 0; t < NT; ++t) {
        char* bufA = lbase + (t & 1) * BUFB;
        char* bufB = bufA + BOFF;
        bf16x8 af[4], bf[NF];

        // ---------------- phase 1: B.kh0 + A.mh0.kh0 ----------------
        #pragma unroll
        for (int j = 0; j < NF; j++) bf[j] = *(const bf16x8*)(bufB + offB[j]);
        #pragma unroll
        for (int i = 0; i < 4; i++)  af[i] = *(const bf16x8*)(bufA + offA[i]);
        if (t + 1 < NT) STAGE_A(t + 1, 1);
        __builtin_amdgcn_s_barrier();
        LGKM0_FENCE();
        __builtin_amdgcn_s_setprio(1);
        #pragma unroll
        for (int i = 0; i < 4; i++)
            #pragma unroll
            for (int j = 0; j < NF; j++)
                acc[i][j] = __builtin_amdgcn_mfma_f32_16x16x32_bf16(
                    af[i], bf[j], acc[i][j], 0, 0, 0);
        __builtin_amdgcn_s_setprio(0);
        __builtin_amdgcn_s_barrier();

        // ---------------- phase 2: A.mh1.kh0 ----------------
        #pragma unroll
        for (int i = 0; i < 4; i++)  af[i] = *(const bf16x8*)(bufA + offA[4 + i]);
        if (t + 2 < NT) STAGE_B(t + 2, 0);
        __builtin_amdgcn_s_barrier();
        LGKM0_FENCE();
        __builtin_amdgcn_s_setprio(1);
        #pragma unroll
        for (int i = 0; i < 4; i++)
            #pragma unroll
            for (int j = 0; j < NF; j++)
                acc[4 + i][j] = __builtin_amdgcn_mfma_f32_16x16x32_bf16(
                    af[i], bf[j], acc[4 + i][j], 0, 0, 0);
        __builtin_amdgcn_s_setprio(0);
        __builtin_amdgcn_s_barrier();

        // ---------------- phase 3: B.kh1 + A.mh0.kh1 ----------------
        #pragma unroll
        for (int j = 0; j < NF; j++) bf[j] = *(const bf16x8*)(bufB + BKH + offB[j]);
        #pragma unroll
        for (int i = 0; i < 4; i++)  af[i] = *(const bf16x8*)(bufA + AKH + offA[i]);
        if (t + 2 < NT) STAGE_A(t + 2, 0);
        __builtin_amdgcn_s_barrier();
        LGKM0_FENCE();
        __builtin_amdgcn_s_setprio(1);
        #pragma unroll
        for (int i = 0; i < 4; i++)
            #pragma unroll
            for (int j = 0; j < NF; j++)
                acc[i][j] = __builtin_amdgcn_mfma_f32_16x16x32_bf16(
                    af[i], bf[j], acc[i][j], 0, 0, 0);
        __builtin_amdgcn_s_setprio(0);
        __builtin_amdgcn_s_barrier();

        // ---------------- phase 4: A.mh1.kh1 + group-end vmcnt ----------------
        #pragma unroll
        for (int i = 0; i < 4; i++)  af[i] = *(const bf16x8*)(bufA + AKH + offA[4 + i]);
        if (t + 2 < NT) STAGE_B(t + 2, 1);
        __builtin_amdgcn_s_barrier();
        LGKM0_FENCE();
        __builtin_amdgcn_s_setprio(1);
        #pragma unroll
        for (int i = 0; i < 4; i++)
            #pragma unroll
            for (int j = 0; j < NF; j++)
                acc[4 + i][j] = __builtin_amdgcn_mfma_f32_16x16x32_bf16(
                    af[i], bf[j], acc[4 + i][j], 0, 0, 0);
        __builtin_amdgcn_s_setprio(0);
        if (t + 2 < NT) asm volatile("s_waitcnt vmcnt(%0)" :: "i"(KEEP) : "memory");
        else            asm volatile("s_waitcnt vmcnt(0)" ::: "memory");
        __builtin_amdgcn_sched_barrier(0);
        __builtin_amdgcn_s_barrier();
    }
    #undef STAGE_A
    #undef STAGE_B

    // epilogue: C/D layout col=lane&15, row=quad*4+reg (m89/m91)
    const long baseRow = bm0 + wm * 128 + quad * 4;
    const long baseCol = bn0 + wn * 16 * NF + m16;
    #pragma unroll
    for (int i = 0; i < 8; i++) {
        #pragma unroll
        for (int j = 0; j < NF; j++) {
            #pragma unroll
            for (int r = 0; r < 4; r++) {
                float v = acc[i][j][r];
                if (RELU2) v = (v > 0.0f) ? v * v : 0.0f;
                const long row = baseRow + i * 16 + r;
                const long col = baseCol + j * 16;
                if (OUT_BF16)
                    ((unsigned short*)Cv)[row * (long)N + col] = f2bf(v);
                else
                    ((float*)Cv)[row * (long)N + col] = v;
            }
        }
    }
}

extern "C" void kernel_launch(void* const* d_in, const int* in_sizes, int n_in,
                              void* d_out, int out_size, void* d_ws, size_t ws_size,
                              hipStream_t stream) {
    (void)in_sizes; (void)n_in; (void)out_size; (void)ws_size;

    const int T = 8192, DIM = 1024, HID = 4096;

    const float* x     = (const float*)d_in[0];  // [T, DIM]
    const float* W_fc  = (const float*)d_in[1];  // [HID, DIM]
    const float* W_prj = (const float*)d_in[2];  // [DIM, HID]
    float* out = (float*)d_out;                  // [T, DIM]

    char* ws = (char*)d_ws;
    unsigned short* h   = (unsigned short*)ws;                  // 64 MiB [T,HID]
    unsigned short* xb  = (unsigned short*)(ws + (64l << 20));  // 16 MiB
    unsigned short* wfb = (unsigned short*)(ws + (80l << 20));  //  8 MiB
    unsigned short* wpb = (unsigned short*)(ws + (88l << 20));  //  8 MiB

    // prepass: all three fp32 -> bf16 in ONE launch
    cvt_all<<<4096, 256, 0, stream>>>(
        (const float4*)x,     (ushort4*)xb,
        (const float4*)W_fc,  (ushort4*)wfb,
        (const float4*)W_prj, (ushort4*)wpb);

    // GEMM1: h = relu(x . W_fc^T)^2   [8192,4096] bf16, NF=4 (BN=256), 512 wgs
    gemm8p<4, true, true><<<dim3(HID / 256, T / 256), dim3(512), 0, stream>>>(
        xb, wfb, h, T, HID, DIM);

    // GEMM2: out = h . W_proj^T       [8192,1024] fp32, NF=2 (BN=128), 256 wgs
    gemm8p<2, false, false><<<dim3(DIM / 128, T / 256), dim3(512), 0, stream>>>(
        h, wpb, out, T, DIM, HID);
}

// Round 2
// 242.641 us; speedup vs baseline: 1.1290x; 1.0093x over previous
//
#include <hip/hip_runtime.h>
#include <stdint.h>

// ============================================================================
// ExpertMLP: out = relu(x @ W_fc^T)^2 @ W_proj^T    (fp32 in/out, bf16 MFMA)
// R8: GEMM1 keeps R7's 256x256 4-phase structure (verified).
//     GEMM2 rebuilt: BM=256 BN=128, 8 waves 4Mx2N (per-wave 64x64 square),
//     2 SKEWED phases/K-tile: ph1 issues kh0+kh1 ds_reads (asm, ordered),
//     lgkmcnt(8) -> MFMA kh0 overlaps kh1 drain; ph2 lgkmcnt(0) -> MFMA kh1
//     with no LDS on critical path. 3 barriers/tile. Counted vmcnt(3).
// ws: h[64Mi] | x_bf[16Mi] | wfc_bf[8Mi] | wproj_bf[8Mi] = 96 MiB.
// ============================================================================

typedef __attribute__((ext_vector_type(8))) short bf16x8;   // 8 bf16 = 4 VGPRs
typedef __attribute__((ext_vector_type(4))) float f32x4;    // MFMA C/D

typedef const __attribute__((address_space(1))) unsigned int* gas_u32p;
typedef __attribute__((address_space(3))) unsigned int* las_u32p;

__device__ __forceinline__ void load16_to_lds(const void* gptr, void* lptr) {
    __builtin_amdgcn_global_load_lds((gas_u32p)gptr, (las_u32p)lptr, 16, 0, 0);
}

__device__ __forceinline__ void dsr128(bf16x8& d, unsigned off) {
    asm volatile("ds_read_b128 %0, %1" : "=v"(d) : "v"(off));
}

__device__ __forceinline__ unsigned short f2bf(float f) {
    unsigned int u = __float_as_uint(f);
    u += 0x7FFFu + ((u >> 16) & 1u);   // RNE; finite inputs
    return (unsigned short)(u >> 16);
}

// --------------------------------------------------------------------------
// Single fused fp32->bf16 prepass: x (2M float4) | W_fc (1M) | W_proj (1M).
// --------------------------------------------------------------------------
__global__ void cvt_all(const float4* __restrict__ x,  ushort4* __restrict__ xb,
                        const float4* __restrict__ wf, ushort4* __restrict__ wfb,
                        const float4* __restrict__ wp, ushort4* __restrict__ wpb)
{
    const int base = blockIdx.x * 1024 + threadIdx.x;
    #pragma unroll
    for (int j = 0; j < 4; j++) {
        const int i = base + j * 256;
        const float4* s; ushort4* d; int k;
        if (i < (1 << 21))            { s = x;  d = xb;  k = i; }
        else if (i < 3 * (1 << 20))   { s = wf; d = wfb; k = i - (1 << 21); }
        else                          { s = wp; d = wpb; k = i - 3 * (1 << 20); }
        float4 v = s[k];
        ushort4 o;
        o.x = f2bf(v.x); o.y = f2bf(v.y); o.z = f2bf(v.z); o.w = f2bf(v.w);
        d[k] = o;
    }
}

#define LGKM0_FENCE() do { \
    asm volatile("s_waitcnt lgkmcnt(0)" ::: "memory"); \
    __builtin_amdgcn_sched_barrier(0); } while (0)

// --------------------------------------------------------------------------
// GEMM1 kernel (unchanged from R7): C[M,N] = A[M,K].B[N,K]^T, 256x256 tile,
// 8 waves 2Mx4N, 4 phases/K-tile, counted vmcnt(KEEP=6).
// --------------------------------------------------------------------------
template<int NF, bool RELU2, bool OUT_BF16>
__global__ __launch_bounds__(512, 2)
void gemm8p(const unsigned short* __restrict__ A,
            const unsigned short* __restrict__ B,
            void* __restrict__ Cv, int M, int N, int K)
{
    constexpr int BM   = 256;
    constexpr int BN   = 64 * NF;
    constexpr int CB   = BN / 128;
    constexpr int AKH  = 16384;
    constexpr int BKH  = BN * 64;
    constexpr int BOFF = 2 * AKH;
    constexpr int BUFB = 2 * AKH + 2 * BKH;
    constexpr int KEEP = 2 + 2 * CB;
    (void)M;

    __shared__ char lds[2 * BUFB];

    const int tid  = threadIdx.x;
    const int lane = tid & 63;
    const int wave = tid >> 6;
    const int wm   = wave >> 2;
    const int wn   = wave & 3;
    const int quad = lane >> 4;
    const int m16  = lane & 15;

    const int gx = gridDim.x;
    int flat = blockIdx.y * gx + blockIdx.x;
    const int cpx = (gx * gridDim.y) >> 3;
    flat = (flat & 7) * cpx + (flat >> 3);
    const long bm0 = (long)(flat / gx) * BM;
    const long bn0 = (long)(flat % gx) * BN;

    const int srow   = tid >> 2;
    const int schunk = (tid & 3) ^ ((tid >> 3) & 3);
    const unsigned short* gA = A + (bm0 + srow) * (long)K + schunk * 8;
    const unsigned short* gB = B + (bn0 + srow) * (long)K + schunk * 8;
    char* lbase = (char*)lds;

    int offA[8], offB[NF];
    #pragma unroll
    for (int i = 0; i < 8; i++) {
        const int lo = (wm * 128 + i * 16 + m16) * 64 + quad * 16;
        offA[i] = lo ^ (((lo >> 7) & 3) << 4);
    }
    #pragma unroll
    for (int j = 0; j < NF; j++) {
        const int lo = (wn * 16 * NF + j * 16 + m16) * 64 + quad * 16;
        offB[j] = lo ^ (((lo >> 7) & 3) << 4);
    }

    f32x4 acc[8][NF];
    #pragma unroll
    for (int i = 0; i < 8; i++)
        #pragma unroll
        for (int j = 0; j < NF; j++)
            acc[i][j] = (f32x4)0.0f;

    const int NT = K >> 6;

    #define STAGE_A(t, kh) do { \
        char* _d = lbase + ((t) & 1) * BUFB + (kh) * AKH + tid * 16; \
        const unsigned short* _s = gA + (long)(t) * 64 + (kh) * 32; \
        load16_to_lds(_s, _d); \
        load16_to_lds(_s + 128l * K, _d + 8192); } while (0)

    #define STAGE_B(t, kh) do { \
        char* _d = lbase + ((t) & 1) * BUFB + BOFF + (kh) * BKH + tid * 16; \
        const unsigned short* _s = gB + (long)(t) * 64 + (kh) * 32; \
        load16_to_lds(_s, _d); \
        if (CB == 2) load16_to_lds(_s + 128l * K, _d + 8192); } while (0)

    STAGE_B(0, 0); STAGE_A(0, 0); STAGE_B(0, 1); STAGE_A(0, 1);
    if (NT > 1) {
        STAGE_B(1, 0); STAGE_A(1, 0); STAGE_B(1, 1);
        asm volatile("s_waitcnt vmcnt(%0)" :: "i"(KEEP) : "memory");
    } else {
        asm volatile("s_waitcnt vmcnt(0)" ::: "memory");
    }
    __builtin_amdgcn_sched_barrier(0);
    __builtin_amdgcn_s_barrier();

    for (int t = 0; t < NT; ++t) {
        char* bufA = lbase + (t & 1) * BUFB;
        char* bufB = bufA + BOFF;
        bf16x8 af[4], bf[NF];

        #pragma unroll
        for (int j = 0; j < NF; j++) bf[j] = *(const bf16x8*)(bufB + offB[j]);
        #pragma unroll
        for (int i = 0; i < 4; i++)  af[i] = *(const bf16x8*)(bufA + offA[i]);
        if (t + 1 < NT) STAGE_A(t + 1, 1);
        __builtin_amdgcn_s_barrier();
        LGKM0_FENCE();
        __builtin_amdgcn_s_setprio(1);
        #pragma unroll
        for (int i = 0; i < 4; i++)
            #pragma unroll
            for (int j = 0; j < NF; j++)
                acc[i][j] = __builtin_amdgcn_mfma_f32_16x16x32_bf16(
                    af[i], bf[j], acc[i][j], 0, 0, 0);
        __builtin_amdgcn_s_setprio(0);
        __builtin_amdgcn_s_barrier();

        #pragma unroll
        for (int i = 0; i < 4; i++)  af[i] = *(const bf16x8*)(bufA + offA[4 + i]);
        if (t + 2 < NT) STAGE_B(t + 2, 0);
        __builtin_amdgcn_s_barrier();
        LGKM0_FENCE();
        __builtin_amdgcn_s_setprio(1);
        #pragma unroll
        for (int i = 0; i < 4; i++)
            #pragma unroll
            for (int j = 0; j < NF; j++)
                acc[4 + i][j] = __builtin_amdgcn_mfma_f32_16x16x32_bf16(
                    af[i], bf[j], acc[4 + i][j], 0, 0, 0);
        __builtin_amdgcn_s_setprio(0);
        __builtin_amdgcn_s_barrier();

        #pragma unroll
        for (int j = 0; j < NF; j++) bf[j] = *(const bf16x8*)(bufB + BKH + offB[j]);
        #pragma unroll
        for (int i = 0; i < 4; i++)  af[i] = *(const bf16x8*)(bufA + AKH + offA[i]);
        if (t + 2 < NT) STAGE_A(t + 2, 0);
        __builtin_amdgcn_s_barrier();
        LGKM0_FENCE();
        __builtin_amdgcn_s_setprio(1);
        #pragma unroll
        for (int i = 0; i < 4; i++)
            #pragma unroll
            for (int j = 0; j < NF; j++)
                acc[i][j] = __builtin_amdgcn_mfma_f32_16x16x32_bf16(
                    af[i], bf[j], acc[i][j], 0, 0, 0);
        __builtin_amdgcn_s_setprio(0);
        __builtin_amdgcn_s_barrier();

        #pragma unroll
        for (int i = 0; i < 4; i++)  af[i] = *(const bf16x8*)(bufA + AKH + offA[4 + i]);
        if (t + 2 < NT) STAGE_B(t + 2, 1);
        __builtin_amdgcn_s_barrier();
        LGKM0_FENCE();
        __builtin_amdgcn_s_setprio(1);
        #pragma unroll
        for (int i = 0; i < 4; i++)
            #pragma unroll
            for (int j = 0; j < NF; j++)
                acc[4 + i][j] = __builtin_amdgcn_mfma_f32_16x16x32_bf16(
                    af[i], bf[j], acc[4 + i][j], 0, 0, 0);
        __builtin_amdgcn_s_setprio(0);
        if (t + 2 < NT) asm volatile("s_waitcnt vmcnt(%0)" :: "i"(KEEP) : "memory");
        else            asm volatile("s_waitcnt vmcnt(0)" ::: "memory");
        __builtin_amdgcn_sched_barrier(0);
        __builtin_amdgcn_s_barrier();
    }
    #undef STAGE_A
    #undef STAGE_B

    const long baseRow = bm0 + wm * 128 + quad * 4;
    const long baseCol = bn0 + wn * 16 * NF + m16;
    #pragma unroll
    for (int i = 0; i < 8; i++) {
        #pragma unroll
        for (int j = 0; j < NF; j++) {
            #pragma unroll
            for (int r = 0; r < 4; r++) {
                float v = acc[i][j][r];
                if (RELU2) v = (v > 0.0f) ? v * v : 0.0f;
                const long row = baseRow + i * 16 + r;
                const long col = baseCol + j * 16;
                if (OUT_BF16)
                    ((unsigned short*)Cv)[row * (long)N + col] = f2bf(v);
                else
                    ((float*)Cv)[row * (long)N + col] = v;
            }
        }
    }
}

// --------------------------------------------------------------------------
// GEMM2 kernel (new): C[M,N] = A[M,K].B[N,K]^T fp32 out, no activation.
// BM=256 BN=128 BK=64, 512 thr, 8 waves 4Mx2N (per-wave 64x64).
// 2 skewed phases/tile:
//   ph1: asm ds_read kh0(8) then kh1(8); stage (t+1).kh1 (other buf, dead
//        since end-of-(t-1) barrier); barrier; lgkmcnt(8) [kh0 ready, LDS
//        in-order completion]; 16 MFMA kh0 (kh1 drains under it); barrier
//        [certifies all waves' kh0 reads complete].
//   ph2: stage (t+2).kh0 (this buf kh0, dead per ph1 barrier); lgkmcnt(0)
//        [free]; 16 MFMA kh1; vmcnt(3) [retires tile t+1: 3 loads issued
//        after it] ; barrier [certifies kh1 reads complete].
// Prologue stages t0.kh0,t0.kh1,t1.kh0 (9 loads), vmcnt(3) retires t0.
// --------------------------------------------------------------------------
__global__ __launch_bounds__(512, 2)
void gemm_skew(const unsigned short* __restrict__ A,
               const unsigned short* __restrict__ B,
               float* __restrict__ C, int M, int N, int K)
{
    constexpr int AKH  = 16384;            // A kh-region: 256r x 32k x 2B
    constexpr int BKH  = 8192;             // B kh-region: 128r x 32k x 2B
    constexpr int BOFF = 2 * AKH;
    constexpr int BUFB = 2 * AKH + 2 * BKH;   // 48 KiB
    (void)M;

    __shared__ char lds[2 * BUFB];            // 96 KiB

    const int tid  = threadIdx.x;
    const int lane = tid & 63;
    const int wave = tid >> 6;
    const int wm   = wave >> 1;            // 0..3 -> rows wm*64
    const int wn   = wave & 1;             // 0..1 -> cols wn*64
    const int quad = lane >> 4;
    const int m16  = lane & 15;

    // T1: XCD swizzle (grid 8x32 = 256 blocks, %8==0)
    const int gx = gridDim.x;
    int flat = blockIdx.y * gx + blockIdx.x;
    const int cpx = (gx * gridDim.y) >> 3;
    flat = (flat & 7) * cpx + (flat >> 3);
    const long bm0 = (long)(flat / gx) * 256;
    const long bn0 = (long)(flat % gx) * 128;

    // staging: row = tid/4 (+128 on A call 2), chunk pre-swizzled at source
    const int srow   = tid >> 2;
    const int schunk = (tid & 3) ^ ((tid >> 3) & 3);
    const unsigned short* gA = A + (bm0 + srow) * (long)K + schunk * 8;
    const unsigned short* gB = B + (bn0 + srow) * (long)K + schunk * 8;

    // swizzled per-kh-region ds_read offsets (row*64 + quad*16, XOR bits 4-5)
    unsigned offA[4], offB[4];
    #pragma unroll
    for (int i = 0; i < 4; i++) {
        const unsigned lo = (unsigned)((wm * 64 + i * 16 + m16) * 64 + quad * 16);
        offA[i] = lo ^ (((lo >> 7) & 3) << 4);
    }
    #pragma unroll
    for (int j = 0; j < 4; j++) {
        const unsigned lo = (unsigned)((wn * 64 + j * 16 + m16) * 64 + quad * 16);
        offB[j] = lo ^ (((lo >> 7) & 3) << 4);
    }

    const unsigned ldsbase =
        (unsigned)(unsigned long long)(las_u32p)(void*)lds;

    f32x4 acc[4][4];
    #pragma unroll
    for (int i = 0; i < 4; i++)
        #pragma unroll
        for (int j = 0; j < 4; j++)
            acc[i][j] = (f32x4)0.0f;

    const int NT = K >> 6;

    #define STAGE2(t, kh) do { \
        char* _dA = (char*)lds + ((t) & 1) * BUFB + (kh) * AKH + tid * 16; \
        const unsigned short* _sA = gA + (long)(t) * 64 + (kh) * 32; \
        load16_to_lds(_sA, _dA); \
        load16_to_lds(_sA + 128l * K, _dA + 8192); \
        char* _dB = (char*)lds + ((t) & 1) * BUFB + BOFF + (kh) * BKH + tid * 16; \
        load16_to_lds(gB + (long)(t) * 64 + (kh) * 32, _dB); } while (0)

    // prologue
    STAGE2(0, 0); STAGE2(0, 1);
    if (NT > 1) {
        STAGE2(1, 0);
        asm volatile("s_waitcnt vmcnt(3)" ::: "memory");
    } else {
        asm volatile("s_waitcnt vmcnt(0)" ::: "memory");
    }
    __builtin_amdgcn_sched_barrier(0);
    __builtin_amdgcn_s_barrier();

    for (int t = 0; t < NT; ++t) {
        const unsigned bufo = ldsbase + (unsigned)((t & 1) * BUFB);
        bf16x8 a0[4], b0[4], a1[4], b1[4];

        // ---- ph1: issue kh0 reads FIRST (lgkmcnt(8) relies on this order) --
        #pragma unroll
        for (int i = 0; i < 4; i++) dsr128(a0[i], bufo + offA[i]);
        #pragma unroll
        for (int j = 0; j < 4; j++) dsr128(b0[j], bufo + BOFF + offB[j]);
        #pragma unroll
        for (int i = 0; i < 4; i++) dsr128(a1[i], bufo + AKH + offA[i]);
        #pragma unroll
        for (int j = 0; j < 4; j++) dsr128(b1[j], bufo + BOFF + BKH + offB[j]);
        if (t + 1 < NT) STAGE2(t + 1, 1);
        __builtin_amdgcn_s_barrier();
        asm volatile("s_waitcnt lgkmcnt(8)" ::: "memory");
        __builtin_amdgcn_sched_barrier(0);
        __builtin_amdgcn_s_setprio(1);
        #pragma unroll
        for (int i = 0; i < 4; i++)
            #pragma unroll
            for (int j = 0; j < 4; j++)
                acc[i][j] = __builtin_amdgcn_mfma_f32_16x16x32_bf16(
                    a0[i], b0[j], acc[i][j], 0, 0, 0);
        __builtin_amdgcn_s_setprio(0);
        __builtin_amdgcn_s_barrier();

        // ---- ph2: kh1 MFMA, reads already drained under ph1 MFMA ----------
        if (t + 2 < NT) STAGE2(t + 2, 0);
        asm volatile("s_waitcnt lgkmcnt(0)" ::: "memory");
        __builtin_amdgcn_sched_barrier(0);
        __builtin_amdgcn_s_setprio(1);
        #pragma unroll
        for (int i = 0; i < 4; i++)
            #pragma unroll
            for (int j = 0; j < 4; j++)
                acc[i][j] = __builtin_amdgcn_mfma_f32_16x16x32_bf16(
                    a1[i], b1[j], acc[i][j], 0, 0, 0);
        __builtin_amdgcn_s_setprio(0);
        if (t + 2 < NT) asm volatile("s_waitcnt vmcnt(3)" ::: "memory");
        else            asm volatile("s_waitcnt vmcnt(0)" ::: "memory");
        __builtin_amdgcn_sched_barrier(0);
        __builtin_amdgcn_s_barrier();
    }
    #undef STAGE2

    // epilogue: C/D layout col=lane&15, row=quad*4+reg
    const long baseRow = bm0 + wm * 64 + quad * 4;
    const long baseCol = bn0 + wn * 64 + m16;
    #pragma unroll
    for (int i = 0; i < 4; i++) {
        #pragma unroll
        for (int j = 0; j < 4; j++) {
            #pragma unroll
            for (int r = 0; r < 4; r++) {
                const long row = baseRow + i * 16 + r;
                const long col = baseCol + j * 16;
                C[row * (long)N + col] = acc[i][j][r];
            }
        }
    }
}

extern "C" void kernel_launch(void* const* d_in, const int* in_sizes, int n_in,
                              void* d_out, int out_size, void* d_ws, size_t ws_size,
                              hipStream_t stream) {
    (void)in_sizes; (void)n_in; (void)out_size; (void)ws_size;

    const int T = 8192, DIM = 1024, HID = 4096;

    const float* x     = (const float*)d_in[0];  // [T, DIM]
    const float* W_fc  = (const float*)d_in[1];  // [HID, DIM]
    const float* W_prj = (const float*)d_in[2];  // [DIM, HID]
    float* out = (float*)d_out;                  // [T, DIM]

    char* ws = (char*)d_ws;
    unsigned short* h   = (unsigned short*)ws;                  // 64 MiB [T,HID]
    unsigned short* xb  = (unsigned short*)(ws + (64l << 20));  // 16 MiB
    unsigned short* wfb = (unsigned short*)(ws + (80l << 20));  //  8 MiB
    unsigned short* wpb = (unsigned short*)(ws + (88l << 20));  //  8 MiB

    // prepass: all three fp32 -> bf16 in ONE launch
    cvt_all<<<4096, 256, 0, stream>>>(
        (const float4*)x,     (ushort4*)xb,
        (const float4*)W_fc,  (ushort4*)wfb,
        (const float4*)W_prj, (ushort4*)wpb);

    // GEMM1: h = relu(x . W_fc^T)^2   [8192,4096] bf16, 256x256 tile
    gemm8p<4, true, true><<<dim3(HID / 256, T / 256), dim3(512), 0, stream>>>(
        xb, wfb, h, T, HID, DIM);

    // GEMM2: out = h . W_proj^T       [8192,1024] fp32, 256x128 skewed kernel
    gemm_skew<<<dim3(DIM / 128, T / 256), dim3(512), 0, stream>>>(
        h, wpb, out, T, DIM, HID);
}

// Round 3
// 240.995 us; speedup vs baseline: 1.1367x; 1.0068x over previous
//
#include <hip/hip_runtime.h>
#include <stdint.h>

// ============================================================================
// ExpertMLP: out = relu(x @ W_fc^T)^2 @ W_proj^T    (fp32 in/out, bf16 MFMA)
// R9: GEMM1 rebuilt with the R8-verified skewed schedule (GEMM2's structure,
//     scaled to 256x256 / 24 reads / 4 MFMA clusters per K-tile):
//       - issue kh0 reads -> lgkm(4) -> c1 MFMA (kh1 reads + staging drain
//         under it) -> lgkm(12) -> c2 -> mid-barrier -> stage kh0(t+2)
//         -> lgkm(4) -> c3 -> lgkm(0) -> c4 -> vmcnt(4) -> end barrier.
//       - 3 barriers/tile (was 8), LDS pipe overlaps MFMA pipe.
//     GEMM2 (gemm_skew) and cvt_all byte-identical to R8.
// ws: h[64Mi] | x_bf[16Mi] | wfc_bf[8Mi] | wproj_bf[8Mi] = 96 MiB.
// ============================================================================

typedef __attribute__((ext_vector_type(8))) short bf16x8;   // 8 bf16 = 4 VGPRs
typedef __attribute__((ext_vector_type(4))) float f32x4;    // MFMA C/D

typedef const __attribute__((address_space(1))) unsigned int* gas_u32p;
typedef __attribute__((address_space(3))) unsigned int* las_u32p;

__device__ __forceinline__ void load16_to_lds(const void* gptr, void* lptr) {
    __builtin_amdgcn_global_load_lds((gas_u32p)gptr, (las_u32p)lptr, 16, 0, 0);
}

__device__ __forceinline__ void dsr128(bf16x8& d, unsigned off) {
    asm volatile("ds_read_b128 %0, %1" : "=v"(d) : "v"(off));
}

__device__ __forceinline__ unsigned short f2bf(float f) {
    unsigned int u = __float_as_uint(f);
    u += 0x7FFFu + ((u >> 16) & 1u);   // RNE; finite inputs
    return (unsigned short)(u >> 16);
}

#define LGKM(n) do { \
    asm volatile("s_waitcnt lgkmcnt(%0)" :: "i"(n) : "memory"); \
    __builtin_amdgcn_sched_barrier(0); } while (0)
#define VMC(n) do { \
    asm volatile("s_waitcnt vmcnt(%0)" :: "i"(n) : "memory"); \
    __builtin_amdgcn_sched_barrier(0); } while (0)

// --------------------------------------------------------------------------
// Single fused fp32->bf16 prepass: x (2M float4) | W_fc (1M) | W_proj (1M).
// --------------------------------------------------------------------------
__global__ void cvt_all(const float4* __restrict__ x,  ushort4* __restrict__ xb,
                        const float4* __restrict__ wf, ushort4* __restrict__ wfb,
                        const float4* __restrict__ wp, ushort4* __restrict__ wpb)
{
    const int base = blockIdx.x * 1024 + threadIdx.x;
    #pragma unroll
    for (int j = 0; j < 4; j++) {
        const int i = base + j * 256;
        const float4* s; ushort4* d; int k;
        if (i < (1 << 21))            { s = x;  d = xb;  k = i; }
        else if (i < 3 * (1 << 20))   { s = wf; d = wfb; k = i - (1 << 21); }
        else                          { s = wp; d = wpb; k = i - 3 * (1 << 20); }
        float4 v = s[k];
        ushort4 o;
        o.x = f2bf(v.x); o.y = f2bf(v.y); o.z = f2bf(v.z); o.w = f2bf(v.w);
        d[k] = o;
    }
}

// --------------------------------------------------------------------------
// GEMM1: C[M,N] = relu(A[M,K].B[N,K]^T)^2, bf16 out. BM=BN=256 BK=64,
// 512 thr, 8 waves 2Mx4N (per-wave 128x64). Skewed 4-cluster schedule.
// Read order per tile (24 ds_read_b128/wave):
//   kh0: a0(4) b0(4) a0b(4)   [issued at top]
//   kh1: a1(4) b1(4) a1b(4)   [issued under c1 MFMA]
// Clusters: c1=a0xb0 (lgkm4), c2=a0b x b0 (lgkm12), c3=a1xb1 (lgkm4),
//           c4=a1b x b1 (lgkm0).  Stages: top (t+1).kh1, mid (t+2).kh0.
// vmcnt(4) at tile end keeps (t+2).kh0 in flight (retires tile t+1).
// --------------------------------------------------------------------------
__global__ __launch_bounds__(512, 2)
void gemm_skew1(const unsigned short* __restrict__ A,
                const unsigned short* __restrict__ B,
                unsigned short* __restrict__ C, int M, int N, int K)
{
    constexpr int AKH  = 16384;            // A kh-region: 256r x 32k x 2B
    constexpr int BKH  = 16384;            // B kh-region: 256r x 32k x 2B
    constexpr int BOFF = 2 * AKH;
    constexpr int BUFB = 2 * AKH + 2 * BKH;   // 64 KiB
    (void)M;

    __shared__ char lds[2 * BUFB];            // 128 KiB

    const int tid  = threadIdx.x;
    const int lane = tid & 63;
    const int wave = tid >> 6;
    const int wm   = wave >> 2;            // 0..1 -> rows wm*128
    const int wn   = wave & 3;             // 0..3 -> cols wn*64
    const int quad = lane >> 4;
    const int m16  = lane & 15;

    // T1: XCD swizzle (grid 16x32 = 512 blocks, %8==0)
    const int gx = gridDim.x;
    int flat = blockIdx.y * gx + blockIdx.x;
    const int cpx = (gx * gridDim.y) >> 3;
    flat = (flat & 7) * cpx + (flat >> 3);
    const long bm0 = (long)(flat / gx) * 256;
    const long bn0 = (long)(flat % gx) * 256;

    // staging: row = tid/4 (+128 on call 2), chunk pre-swizzled at source
    const int srow   = tid >> 2;
    const int schunk = (tid & 3) ^ ((tid >> 3) & 3);
    const unsigned short* gA = A + (bm0 + srow) * (long)K + schunk * 8;
    const unsigned short* gB = B + (bn0 + srow) * (long)K + schunk * 8;

    // swizzled per-kh-region ds_read offsets (row*64 + quad*16, XOR bits 4-5)
    unsigned offA[8], offB[4];
    #pragma unroll
    for (int i = 0; i < 8; i++) {
        const unsigned lo = (unsigned)((wm * 128 + i * 16 + m16) * 64 + quad * 16);
        offA[i] = lo ^ (((lo >> 7) & 3) << 4);
    }
    #pragma unroll
    for (int j = 0; j < 4; j++) {
        const unsigned lo = (unsigned)((wn * 64 + j * 16 + m16) * 64 + quad * 16);
        offB[j] = lo ^ (((lo >> 7) & 3) << 4);
    }

    const unsigned ldsbase =
        (unsigned)(unsigned long long)(las_u32p)(void*)lds;

    f32x4 acc[8][4];
    #pragma unroll
    for (int i = 0; i < 8; i++)
        #pragma unroll
        for (int j = 0; j < 4; j++)
            acc[i][j] = (f32x4)0.0f;

    const int NT = K >> 6;

    #define STG1(t, kh) do { \
        char* _dA = (char*)lds + ((t) & 1) * BUFB + (kh) * AKH + tid * 16; \
        const unsigned short* _sA = gA + (long)(t) * 64 + (kh) * 32; \
        load16_to_lds(_sA, _dA); \
        load16_to_lds(_sA + 128l * K, _dA + 8192); \
        char* _dB = (char*)lds + ((t) & 1) * BUFB + BOFF + (kh) * BKH + tid * 16; \
        const unsigned short* _sB = gB + (long)(t) * 64 + (kh) * 32; \
        load16_to_lds(_sB, _dB); \
        load16_to_lds(_sB + 128l * K, _dB + 8192); } while (0)

    // prologue: t0 fully + t1.kh0; vmcnt(4) retires t0, keeps t1.kh0 in flight
    STG1(0, 0); STG1(0, 1);
    if (NT > 1) {
        STG1(1, 0);
        VMC(4);
    } else {
        VMC(0);
    }
    __builtin_amdgcn_s_barrier();

    for (int t = 0; t < NT; ++t) {
        const unsigned bufo = ldsbase + (unsigned)((t & 1) * BUFB);
        bf16x8 a0[4], b0[4], a0b[4], a1[4], b1[4], a1b[4];

        // ---- issue kh0 reads (order matters for counted lgkm) ----
        #pragma unroll
        for (int i = 0; i < 4; i++) dsr128(a0[i],  bufo + offA[i]);
        #pragma unroll
        for (int j = 0; j < 4; j++) dsr128(b0[j],  bufo + BOFF + offB[j]);
        #pragma unroll
        for (int i = 0; i < 4; i++) dsr128(a0b[i], bufo + offA[4 + i]);
        if (t + 1 < NT) STG1(t + 1, 1);     // (t+1).kh1 -> other buf (dead)
        __builtin_amdgcn_s_barrier();

        // ---- c1: a0 x b0 (needs first 8 reads; 4 may still be in flight) ----
        LGKM(4);
        __builtin_amdgcn_s_setprio(1);
        #pragma unroll
        for (int i = 0; i < 4; i++)
            #pragma unroll
            for (int j = 0; j < 4; j++)
                acc[i][j] = __builtin_amdgcn_mfma_f32_16x16x32_bf16(
                    a0[i], b0[j], acc[i][j], 0, 0, 0);
        __builtin_amdgcn_s_setprio(0);

        // ---- issue kh1 reads (drain under c1/c2) ----
        #pragma unroll
        for (int i = 0; i < 4; i++) dsr128(a1[i],  bufo + AKH + offA[i]);
        #pragma unroll
        for (int j = 0; j < 4; j++) dsr128(b1[j],  bufo + BOFF + BKH + offB[j]);
        #pragma unroll
        for (int i = 0; i < 4; i++) dsr128(a1b[i], bufo + AKH + offA[4 + i]);

        // ---- c2: a0b x b0 (all kh0 done when <=12 outstanding) ----
        LGKM(12);
        __builtin_amdgcn_s_setprio(1);
        #pragma unroll
        for (int i = 0; i < 4; i++)
            #pragma unroll
            for (int j = 0; j < 4; j++)
                acc[4 + i][j] = __builtin_amdgcn_mfma_f32_16x16x32_bf16(
                    a0b[i], b0[j], acc[4 + i][j], 0, 0, 0);
        __builtin_amdgcn_s_setprio(0);
        __builtin_amdgcn_s_barrier();       // all waves' kh0 reads complete

        if (t + 2 < NT) STG1(t + 2, 0);     // (t+2).kh0 -> current buf (dead)

        // ---- c3: a1 x b1 (first 8 kh1 reads done when <=4 outstanding) ----
        LGKM(4);
        __builtin_amdgcn_s_setprio(1);
        #pragma unroll
        for (int i = 0; i < 4; i++)
            #pragma unroll
            for (int j = 0; j < 4; j++)
                acc[i][j] = __builtin_amdgcn_mfma_f32_16x16x32_bf16(
                    a1[i], b1[j], acc[i][j], 0, 0, 0);
        __builtin_amdgcn_s_setprio(0);

        // ---- c4: a1b x b1 ----
        LGKM(0);
        __builtin_amdgcn_s_setprio(1);
        #pragma unroll
        for (int i = 0; i < 4; i++)
            #pragma unroll
            for (int j = 0; j < 4; j++)
                acc[4 + i][j] = __builtin_amdgcn_mfma_f32_16x16x32_bf16(
                    a1b[i], b1[j], acc[4 + i][j], 0, 0, 0);
        __builtin_amdgcn_s_setprio(0);

        if (t + 2 < NT) VMC(4);             // retires tile t+1 completely
        else            VMC(0);
        __builtin_amdgcn_s_barrier();
    }
    #undef STG1

    // epilogue: relu^2 + bf16 store; C/D layout col=lane&15, row=quad*4+reg
    const long baseRow = bm0 + wm * 128 + quad * 4;
    const long baseCol = bn0 + wn * 64 + m16;
    #pragma unroll
    for (int i = 0; i < 8; i++) {
        #pragma unroll
        for (int j = 0; j < 4; j++) {
            #pragma unroll
            for (int r = 0; r < 4; r++) {
                float v = acc[i][j][r];
                v = (v > 0.0f) ? v * v : 0.0f;
                const long row = baseRow + i * 16 + r;
                const long col = baseCol + j * 16;
                C[row * (long)N + col] = f2bf(v);
            }
        }
    }
}

// --------------------------------------------------------------------------
// GEMM2 kernel (unchanged from R8): C[M,N] = A[M,K].B[N,K]^T fp32 out.
// BM=256 BN=128 BK=64, 512 thr, 8 waves 4Mx2N (per-wave 64x64), skewed.
// --------------------------------------------------------------------------
__global__ __launch_bounds__(512, 2)
void gemm_skew(const unsigned short* __restrict__ A,
               const unsigned short* __restrict__ B,
               float* __restrict__ C, int M, int N, int K)
{
    constexpr int AKH  = 16384;            // A kh-region: 256r x 32k x 2B
    constexpr int BKH  = 8192;             // B kh-region: 128r x 32k x 2B
    constexpr int BOFF = 2 * AKH;
    constexpr int BUFB = 2 * AKH + 2 * BKH;   // 48 KiB
    (void)M;

    __shared__ char lds[2 * BUFB];            // 96 KiB

    const int tid  = threadIdx.x;
    const int lane = tid & 63;
    const int wave = tid >> 6;
    const int wm   = wave >> 1;            // 0..3 -> rows wm*64
    const int wn   = wave & 1;             // 0..1 -> cols wn*64
    const int quad = lane >> 4;
    const int m16  = lane & 15;

    // T1: XCD swizzle (grid 8x32 = 256 blocks, %8==0)
    const int gx = gridDim.x;
    int flat = blockIdx.y * gx + blockIdx.x;
    const int cpx = (gx * gridDim.y) >> 3;
    flat = (flat & 7) * cpx + (flat >> 3);
    const long bm0 = (long)(flat / gx) * 256;
    const long bn0 = (long)(flat % gx) * 128;

    // staging: row = tid/4 (+128 on A call 2), chunk pre-swizzled at source
    const int srow   = tid >> 2;
    const int schunk = (tid & 3) ^ ((tid >> 3) & 3);
    const unsigned short* gA = A + (bm0 + srow) * (long)K + schunk * 8;
    const unsigned short* gB = B + (bn0 + srow) * (long)K + schunk * 8;

    // swizzled per-kh-region ds_read offsets (row*64 + quad*16, XOR bits 4-5)
    unsigned offA[4], offB[4];
    #pragma unroll
    for (int i = 0; i < 4; i++) {
        const unsigned lo = (unsigned)((wm * 64 + i * 16 + m16) * 64 + quad * 16);
        offA[i] = lo ^ (((lo >> 7) & 3) << 4);
    }
    #pragma unroll
    for (int j = 0; j < 4; j++) {
        const unsigned lo = (unsigned)((wn * 64 + j * 16 + m16) * 64 + quad * 16);
        offB[j] = lo ^ (((lo >> 7) & 3) << 4);
    }

    const unsigned ldsbase =
        (unsigned)(unsigned long long)(las_u32p)(void*)lds;

    f32x4 acc[4][4];
    #pragma unroll
    for (int i = 0; i < 4; i++)
        #pragma unroll
        for (int j = 0; j < 4; j++)
            acc[i][j] = (f32x4)0.0f;

    const int NT = K >> 6;

    #define STAGE2(t, kh) do { \
        char* _dA = (char*)lds + ((t) & 1) * BUFB + (kh) * AKH + tid * 16; \
        const unsigned short* _sA = gA + (long)(t) * 64 + (kh) * 32; \
        load16_to_lds(_sA, _dA); \
        load16_to_lds(_sA + 128l * K, _dA + 8192); \
        char* _dB = (char*)lds + ((t) & 1) * BUFB + BOFF + (kh) * BKH + tid * 16; \
        load16_to_lds(gB + (long)(t) * 64 + (kh) * 32, _dB); } while (0)

    // prologue
    STAGE2(0, 0); STAGE2(0, 1);
    if (NT > 1) {
        STAGE2(1, 0);
        asm volatile("s_waitcnt vmcnt(3)" ::: "memory");
    } else {
        asm volatile("s_waitcnt vmcnt(0)" ::: "memory");
    }
    __builtin_amdgcn_sched_barrier(0);
    __builtin_amdgcn_s_barrier();

    for (int t = 0; t < NT; ++t) {
        const unsigned bufo = ldsbase + (unsigned)((t & 1) * BUFB);
        bf16x8 a0[4], b0[4], a1[4], b1[4];

        // ---- ph1: issue kh0 reads FIRST (lgkmcnt(8) relies on this order) --
        #pragma unroll
        for (int i = 0; i < 4; i++) dsr128(a0[i], bufo + offA[i]);
        #pragma unroll
        for (int j = 0; j < 4; j++) dsr128(b0[j], bufo + BOFF + offB[j]);
        #pragma unroll
        for (int i = 0; i < 4; i++) dsr128(a1[i], bufo + AKH + offA[i]);
        #pragma unroll
        for (int j = 0; j < 4; j++) dsr128(b1[j], bufo + BOFF + BKH + offB[j]);
        if (t + 1 < NT) STAGE2(t + 1, 1);
        __builtin_amdgcn_s_barrier();
        asm volatile("s_waitcnt lgkmcnt(8)" ::: "memory");
        __builtin_amdgcn_sched_barrier(0);
        __builtin_amdgcn_s_setprio(1);
        #pragma unroll
        for (int i = 0; i < 4; i++)
            #pragma unroll
            for (int j = 0; j < 4; j++)
                acc[i][j] = __builtin_amdgcn_mfma_f32_16x16x32_bf16(
                    a0[i], b0[j], acc[i][j], 0, 0, 0);
        __builtin_amdgcn_s_setprio(0);
        __builtin_amdgcn_s_barrier();

        // ---- ph2: kh1 MFMA, reads already drained under ph1 MFMA ----------
        if (t + 2 < NT) STAGE2(t + 2, 0);
        asm volatile("s_waitcnt lgkmcnt(0)" ::: "memory");
        __builtin_amdgcn_sched_barrier(0);
        __builtin_amdgcn_s_setprio(1);
        #pragma unroll
        for (int i = 0; i < 4; i++)
            #pragma unroll
            for (int j = 0; j < 4; j++)
                acc[i][j] = __builtin_amdgcn_mfma_f32_16x16x32_bf16(
                    a1[i], b1[j], acc[i][j], 0, 0, 0);
        __builtin_amdgcn_s_setprio(0);
        if (t + 2 < NT) asm volatile("s_waitcnt vmcnt(3)" ::: "memory");
        else            asm volatile("s_waitcnt vmcnt(0)" ::: "memory");
        __builtin_amdgcn_sched_barrier(0);
        __builtin_amdgcn_s_barrier();
    }
    #undef STAGE2

    // epilogue: C/D layout col=lane&15, row=quad*4+reg
    const long baseRow = bm0 + wm * 64 + quad * 4;
    const long baseCol = bn0 + wn * 64 + m16;
    #pragma unroll
    for (int i = 0; i < 4; i++) {
        #pragma unroll
        for (int j = 0; j < 4; j++) {
            #pragma unroll
            for (int r = 0; r < 4; r++) {
                const long row = baseRow + i * 16 + r;
                const long col = baseCol + j * 16;
                C[row * (long)N + col] = acc[i][j][r];
            }
        }
    }
}

extern "C" void kernel_launch(void* const* d_in, const int* in_sizes, int n_in,
                              void* d_out, int out_size, void* d_ws, size_t ws_size,
                              hipStream_t stream) {
    (void)in_sizes; (void)n_in; (void)out_size; (void)ws_size;

    const int T = 8192, DIM = 1024, HID = 4096;

    const float* x     = (const float*)d_in[0];  // [T, DIM]
    const float* W_fc  = (const float*)d_in[1];  // [HID, DIM]
    const float* W_prj = (const float*)d_in[2];  // [DIM, HID]
    float* out = (float*)d_out;                  // [T, DIM]

    char* ws = (char*)d_ws;
    unsigned short* h   = (unsigned short*)ws;                  // 64 MiB [T,HID]
    unsigned short* xb  = (unsigned short*)(ws + (64l << 20));  // 16 MiB
    unsigned short* wfb = (unsigned short*)(ws + (80l << 20));  //  8 MiB
    unsigned short* wpb = (unsigned short*)(ws + (88l << 20));  //  8 MiB

    // prepass: all three fp32 -> bf16 in ONE launch
    cvt_all<<<4096, 256, 0, stream>>>(
        (const float4*)x,     (ushort4*)xb,
        (const float4*)W_fc,  (ushort4*)wfb,
        (const float4*)W_prj, (ushort4*)wpb);

    // GEMM1: h = relu(x . W_fc^T)^2   [8192,4096] bf16, 256x256 skewed kernel
    gemm_skew1<<<dim3(HID / 256, T / 256), dim3(512), 0, stream>>>(
        xb, wfb, h, T, HID, DIM);

    // GEMM2: out = h . W_proj^T       [8192,1024] fp32, 256x128 skewed kernel
    gemm_skew<<<dim3(DIM / 128, T / 256), dim3(512), 0, stream>>>(
        h, wpb, out, T, DIM, HID);
}